// Round 1
// 564.641 us; speedup vs baseline: 1.0118x; 1.0118x over previous
//
#include <hip/hip_runtime.h>

// Problem dims
#define Bn   256
#define Tn   1024
#define INn  128
#define Hn   10
#define OUTn 128
#define BTn  (Bn * Tn)   // 262144 rows

// =====================================================================
// K1: xp0[b,t,j] = sum_i x[b,t,i]*W_ih0[j,i] + b_ih0[j] + b_hh0[j]
// (unchanged — controlled experiment; K2 is the variable)
// =====================================================================
__global__ __launch_bounds__(256) void k1_inproj(
    const float* __restrict__ x,
    const float* __restrict__ Wih0,
    const float* __restrict__ bih0,
    const float* __restrict__ bhh0,
    float* __restrict__ xp0)
{
    __shared__ float Ws[Hn][INn];   // 5 KB
    __shared__ float bs[16];
    const int tid = threadIdx.x;
    for (int idx = tid; idx < Hn * INn; idx += 256)
        Ws[idx / INn][idx % INn] = Wih0[idx];
    if (tid < 16) bs[tid] = (tid < Hn) ? (bih0[tid] + bhh0[tid]) : 0.f;
    __syncthreads();

    const int row = blockIdx.x * 256 + tid;                 // grid = BTn/256
    const float4* xr = reinterpret_cast<const float4*>(x + (size_t)row * INn);

    float acc[Hn];
    #pragma unroll
    for (int j = 0; j < Hn; ++j) acc[j] = bs[j];

    #pragma unroll
    for (int c = 0; c < INn / 4; ++c) {
        float4 v = xr[c];
        #pragma unroll
        for (int j = 0; j < Hn; ++j) {
            acc[j] = fmaf(v.x, Ws[j][c * 4 + 0], acc[j]);
            acc[j] = fmaf(v.y, Ws[j][c * 4 + 1], acc[j]);
            acc[j] = fmaf(v.z, Ws[j][c * 4 + 2], acc[j]);
            acc[j] = fmaf(v.w, Ws[j][c * 4 + 3], acc[j]);
        }
    }
    float4* op = reinterpret_cast<float4*>(xp0 + (size_t)row * 16);
    op[0] = make_float4(acc[0], acc[1], acc[2], acc[3]);
    op[1] = make_float4(acc[4], acc[5], acc[6], acc[7]);
    op[2] = make_float4(acc[8], acc[9], 0.f, 0.f);
    op[3] = make_float4(0.f, 0.f, 0.f, 0.f);
}

// =====================================================================
// K2 v3: state exchange via v_readlane -> SGPR broadcast. No LDS on the
// serial chain (round-3 theory: the ds_write->ds_read->lgkmcnt(0)
// round-trip was ~600 of the 685 cyc/step at 1 wave/CU).
//
// One chain (batch element) per wave (SGPR broadcasts are wave-uniform,
// so a wave cannot carry two chains). Layout in the state VGPR `vh`:
//   lanes 0..9  : h1[t-1][j]   (layer-1 state)
//   lanes 16..25: h2[t-2][j]   (layer-2 state, pipelined 1 step behind)
//   lanes 32..63: harmless mirror of 0..31 (masked from all stores)
// Per step: 20x v_readlane (VALU pipe, pulls the full state into SGPRs,
// shared by BOTH halves' FMAs) -> 20 FMA (SGPR x per-lane-weight) ->
// relu -> vh. Zero memory ops on the dependency chain.
//   lanes 0..15 ("half 0"): h1[t][j],  A=W_hh0 row j, B=0
//   lanes 16..31("half 1"): h2[t-1][j],A=W_ih1 row j, B=W_hh1 row j
// =====================================================================
static __device__ __forceinline__ float rdlane(float v, int l) {
    return __int_as_float(__builtin_amdgcn_readlane(__float_as_int(v), l));
}

__global__ __launch_bounds__(64, 1) void k2_recur(
    const float* __restrict__ xp0,
    const float* __restrict__ Whh0,
    const float* __restrict__ Wih1,
    const float* __restrict__ Whh1,
    const float* __restrict__ bih1,
    const float* __restrict__ bhh1,
    float* __restrict__ h2seq,
    float* __restrict__ hidden)   // [2, Bn, Hn] f32 (tail of d_out)
{
    const int lane = threadIdx.x;          // 0..63; lanes 32..63 are idle mirrors
    const int half = (lane >> 4) & 1;
    const int j    = lane & 15;
    const int jc   = (j < Hn) ? j : (Hn - 1);
    const int b    = blockIdx.x;           // grid = Bn = 256

    float Aw[Hn], Bw[Hn];
    #pragma unroll
    for (int k = 0; k < Hn; ++k) {
        Aw[k] = half ? Wih1[jc * Hn + k] : Whh0[jc * Hn + k];
        Bw[k] = half ? Whh1[jc * Hn + k] : 0.f;
    }
    const float bias1 = bih1[jc] + bhh1[jc];
    const bool st = (lane >= 16) && (lane < 16 + Hn);  // h2 store lanes (mask mirrors!)
    const bool s1 = (lane < Hn);                       // h1 hidden-state lanes

    const float* xp  = xp0 + (size_t)b * Tn * 16 + j;
    float*       h2w = h2seq + (size_t)b * Tn * Hn + j - Hn;  // pre-offset: step t stores t-1

    float vh = 0.f;   // state register

    float xbuf[8];
    #pragma unroll
    for (int u = 0; u < 8; ++u) xbuf[u] = xp[u * 16];

    for (int tb = 0; tb < Tn / 8; ++tb) {
        #pragma unroll
        for (int u = 0; u < 8; ++u) {
            const int t = tb * 8 + u;
            const float xv = xbuf[u];
            if (tb < Tn / 8 - 1) xbuf[u] = xp[(u + 8) * 16];

            // broadcast full state into SGPRs (wave-uniform, feeds both halves)
            float sa[Hn], sb[Hn];
            #pragma unroll
            for (int k = 0; k < Hn; ++k) sa[k] = rdlane(vh, k);        // h1[t-1]
            #pragma unroll
            for (int k = 0; k < Hn; ++k) sb[k] = rdlane(vh, 16 + k);   // h2[t-2]

            float c1a = half ? bias1 : xv;
            float c1b = 0.f, c2a = 0.f, c2b = 0.f;
            #pragma unroll
            for (int k = 0; k < Hn; ++k) {
                if (k & 1) { c1b = fmaf(Aw[k], sa[k], c1b); c2b = fmaf(Bw[k], sb[k], c2b); }
                else       { c1a = fmaf(Aw[k], sa[k], c1a); c2a = fmaf(Bw[k], sb[k], c2a); }
            }
            const float hn = fmaxf((c1a + c1b) + (c2a + c2b), 0.f);

            // at t==0, half1's result is h2[-1] (undefined) -> keep state 0
            vh = (half && t == 0) ? 0.f : hn;

            if (st && t > 0) h2w[0] = hn;   // h2seq[b, t-1, j]
            h2w += Hn;
        }
        xp += 128;   // advance 8 timesteps (16 floats each)
    }

    // Epilogue: h2[T-1] = relu(bias1 + W_ih1*h1[T-1] + W_hh1*h2[T-2])
    {
        float sa[Hn], sb[Hn];
        #pragma unroll
        for (int k = 0; k < Hn; ++k) sa[k] = rdlane(vh, k);        // h1[T-1]
        #pragma unroll
        for (int k = 0; k < Hn; ++k) sb[k] = rdlane(vh, 16 + k);   // h2[T-2]
        float c1a = bias1, c1b = 0.f, c2a = 0.f, c2b = 0.f;
        #pragma unroll
        for (int k = 0; k < Hn; ++k) {
            if (k & 1) { c1b = fmaf(Aw[k], sa[k], c1b); c2b = fmaf(Bw[k], sb[k], c2b); }
            else       { c1a = fmaf(Aw[k], sa[k], c1a); c2a = fmaf(Bw[k], sb[k], c2a); }
        }
        const float hn = fmaxf((c1a + c1b) + (c2a + c2b), 0.f);
        if (st) {
            h2w[0] = hn;                                  // h2seq[b, T-1, j]
            hidden[Bn * Hn + b * Hn + (lane - 16)] = hn;  // hidden[1] = h2[T-1]
        }
        if (s1) {
            hidden[b * Hn + lane] = vh;                   // hidden[0] = h1[T-1]
        }
    }
}

// =====================================================================
// K3: logits = h2seq * W_lin^T + b_lin, softmax over 128, f32 out.
// (unchanged — controlled experiment)
// =====================================================================
__global__ __launch_bounds__(256) void k3_outproj(
    const float* __restrict__ h2seq,
    const float* __restrict__ Wlin,
    const float* __restrict__ blin,
    float* __restrict__ out)
{
    const int lane = threadIdx.x & 63;
    const int wid  = blockIdx.x * 4 + (threadIdx.x >> 6);  // grid=1024 -> 4096 waves
    const int g    = lane >> 4;
    const int i    = lane & 15;

    float wl[8][Hn], bl[8];
    #pragma unroll
    for (int s = 0; s < 8; ++s) {
        const int o = i * 8 + s;
        bl[s] = blin[o];
        #pragma unroll
        for (int k = 0; k < Hn; ++k) wl[s][k] = Wlin[o * Hn + k];
    }

    for (int r = wid * 4 + g; r < BTn; r += 4096 * 4) {
        const float hv = (i < Hn) ? h2seq[(size_t)r * Hn + i] : 0.f;
        float acc[8];
        #pragma unroll
        for (int s = 0; s < 8; ++s) acc[s] = bl[s];
        #pragma unroll
        for (int k = 0; k < Hn; ++k) {
            const float hk = __shfl(hv, k, 16);
            #pragma unroll
            for (int s = 0; s < 8; ++s) acc[s] = fmaf(wl[s][k], hk, acc[s]);
        }
        // softmax over this row's 128 logits (16 lanes x 8)
        float m = acc[0];
        #pragma unroll
        for (int s = 1; s < 8; ++s) m = fmaxf(m, acc[s]);
        #pragma unroll
        for (int off = 1; off < 16; off <<= 1) m = fmaxf(m, __shfl_xor(m, off, 16));
        float e[8], ssum = 0.f;
        #pragma unroll
        for (int s = 0; s < 8; ++s) { e[s] = __expf(acc[s] - m); ssum += e[s]; }
        #pragma unroll
        for (int off = 1; off < 16; off <<= 1) ssum += __shfl_xor(ssum, off, 16);
        const float inv = 1.0f / ssum;
        float4* op = reinterpret_cast<float4*>(out + (size_t)r * OUTn + i * 8);
        op[0] = make_float4(e[0] * inv, e[1] * inv, e[2] * inv, e[3] * inv);
        op[1] = make_float4(e[4] * inv, e[5] * inv, e[6] * inv, e[7] * inv);
    }
}

extern "C" void kernel_launch(void* const* d_in, const int* in_sizes, int n_in,
                              void* d_out, int out_size, void* d_ws, size_t ws_size,
                              hipStream_t stream)
{
    const float* x    = (const float*)d_in[0];
    const float* Wih0 = (const float*)d_in[1];
    const float* Whh0 = (const float*)d_in[2];
    const float* bih0 = (const float*)d_in[3];
    const float* bhh0 = (const float*)d_in[4];
    const float* Wih1 = (const float*)d_in[5];
    const float* Whh1 = (const float*)d_in[6];
    const float* bih1 = (const float*)d_in[7];
    const float* bhh1 = (const float*)d_in[8];
    const float* Wlin = (const float*)d_in[9];
    const float* blin = (const float*)d_in[10];

    float* out    = (float*)d_out;
    float* hidden = out + (size_t)BTn * OUTn;    // [2,B,H] tail of d_out

    float* xp0   = (float*)d_ws;                 // BTn*16 f32 = 16.8 MB
    float* h2seq = xp0 + (size_t)BTn * 16;       // BTn*10 f32 = 10.5 MB

    k1_inproj<<<BTn / 256, 256, 0, stream>>>(x, Wih0, bih0, bhh0, xp0);
    k2_recur<<<Bn, 64, 0, stream>>>(xp0, Whh0, Wih1, Whh1, bih1, bhh1, h2seq, hidden);
    k3_outproj<<<1024, 256, 0, stream>>>(h2seq, Wlin, blin, out);
}

// Round 2
// 542.029 us; speedup vs baseline: 1.0540x; 1.0417x over previous
//
#include <hip/hip_runtime.h>

// Problem dims
#define Bn   256
#define Tn   1024
#define INn  128
#define Hn   10
#define OUTn 128
#define BTn  (Bn * Tn)   // 262144 rows

// =====================================================================
// K1: xp0[b,t,j] = sum_i x[b,t,i]*W_ih0[j,i] + b_ih0[j] + b_hh0[j]
// (unchanged — controlled experiment; K2 is the variable)
// =====================================================================
__global__ __launch_bounds__(256) void k1_inproj(
    const float* __restrict__ x,
    const float* __restrict__ Wih0,
    const float* __restrict__ bih0,
    const float* __restrict__ bhh0,
    float* __restrict__ xp0)
{
    __shared__ float Ws[Hn][INn];   // 5 KB
    __shared__ float bs[16];
    const int tid = threadIdx.x;
    for (int idx = tid; idx < Hn * INn; idx += 256)
        Ws[idx / INn][idx % INn] = Wih0[idx];
    if (tid < 16) bs[tid] = (tid < Hn) ? (bih0[tid] + bhh0[tid]) : 0.f;
    __syncthreads();

    const int row = blockIdx.x * 256 + tid;                 // grid = BTn/256
    const float4* xr = reinterpret_cast<const float4*>(x + (size_t)row * INn);

    float acc[Hn];
    #pragma unroll
    for (int j = 0; j < Hn; ++j) acc[j] = bs[j];

    #pragma unroll
    for (int c = 0; c < INn / 4; ++c) {
        float4 v = xr[c];
        #pragma unroll
        for (int j = 0; j < Hn; ++j) {
            acc[j] = fmaf(v.x, Ws[j][c * 4 + 0], acc[j]);
            acc[j] = fmaf(v.y, Ws[j][c * 4 + 1], acc[j]);
            acc[j] = fmaf(v.z, Ws[j][c * 4 + 2], acc[j]);
            acc[j] = fmaf(v.w, Ws[j][c * 4 + 3], acc[j]);
        }
    }
    float4* op = reinterpret_cast<float4*>(xp0 + (size_t)row * 16);
    op[0] = make_float4(acc[0], acc[1], acc[2], acc[3]);
    op[1] = make_float4(acc[4], acc[5], acc[6], acc[7]);
    op[2] = make_float4(acc[8], acc[9], 0.f, 0.f);
    op[3] = make_float4(0.f, 0.f, 0.f, 0.f);
}

// =====================================================================
// K2 v4: readlane state exchange + two fixes for the serial chain:
//  (a) weights PINNED into VGPRs via asm "+v" — round-1 showed
//      VGPR_Count=24, i.e. the compiler was rematerializing the
//      loop-invariant weight loads INSIDE the time loop, putting
//      global-load latency (~600 cy) on the recurrence every step.
//      The asm makes the values opaque -> must stay in registers.
//  (b) h2 stores batched per 8-step block from distinct registers
//      (h2buf[8]) — kills per-step vmcnt WAR waits on the stored reg.
// Layout in state VGPR `vh`:
//   lanes 0..9  : h1[t-1][j];  lanes 16..25: h2[t-2][j] (1 step behind)
//   lanes 0..15 ("half 0"): h1[t][j],  A=W_hh0 row j, B=0
//   lanes 16..31("half 1"): h2[t-1][j],A=W_ih1 row j, B=W_hh1 row j
// =====================================================================
static __device__ __forceinline__ float rdlane(float v, int l) {
    return __int_as_float(__builtin_amdgcn_readlane(__float_as_int(v), l));
}
static __device__ __forceinline__ void pinv(float& v) {
    asm volatile("" : "+v"(v));
}

__global__ __launch_bounds__(64, 1) void k2_recur(
    const float* __restrict__ xp0,
    const float* __restrict__ Whh0,
    const float* __restrict__ Wih1,
    const float* __restrict__ Whh1,
    const float* __restrict__ bih1,
    const float* __restrict__ bhh1,
    float* __restrict__ h2seq,
    float* __restrict__ hidden)   // [2, Bn, Hn] f32 (tail of d_out)
{
    const int lane = threadIdx.x;          // 0..63; lanes 32..63 idle mirrors
    const int half = (lane >> 4) & 1;
    const int j    = lane & 15;
    const int jc   = (j < Hn) ? j : (Hn - 1);
    const int b    = blockIdx.x;           // grid = Bn = 256

    float Aw[Hn], Bw[Hn];
    #pragma unroll
    for (int k = 0; k < Hn; ++k) {
        Aw[k] = half ? Wih1[jc * Hn + k] : Whh0[jc * Hn + k];
        Bw[k] = half ? Whh1[jc * Hn + k] : 0.f;
    }
    float bias1 = bih1[jc] + bhh1[jc];

    // force the weights to be materialized and HELD in VGPRs
    #pragma unroll
    for (int k = 0; k < Hn; ++k) { pinv(Aw[k]); pinv(Bw[k]); }
    pinv(bias1);

    const bool st = (lane >= 16) && (lane < 16 + Hn);  // h2 store lanes
    const bool s1 = (lane < Hn);                       // h1 hidden lanes

    const float* xp = xp0 + (size_t)b * Tn * 16 + j;
    float* const h2base = h2seq + (size_t)b * Tn * Hn + (lane & 15); // st lanes: j

    float vh = 0.f;   // state register

    float xbuf[8];
    #pragma unroll
    for (int u = 0; u < 8; ++u) xbuf[u] = xp[u * 16];

    for (int tb = 0; tb < Tn / 8; ++tb) {
        float h2buf[8];
        #pragma unroll
        for (int u = 0; u < 8; ++u) {
            const int t = tb * 8 + u;
            const float xv = xbuf[u];
            if (tb < Tn / 8 - 1) xbuf[u] = xp[(u + 8) * 16];

            // broadcast full state into SGPRs (feeds both halves)
            float sa[Hn], sb[Hn];
            #pragma unroll
            for (int k = 0; k < Hn; ++k) sa[k] = rdlane(vh, k);        // h1[t-1]
            #pragma unroll
            for (int k = 0; k < Hn; ++k) sb[k] = rdlane(vh, 16 + k);   // h2[t-2]

            float c1a = half ? bias1 : xv;
            float c1b = 0.f, c2a = 0.f, c2b = 0.f;
            #pragma unroll
            for (int k = 0; k < Hn; ++k) {
                if (k & 1) { c1b = fmaf(Aw[k], sa[k], c1b); c2b = fmaf(Bw[k], sb[k], c2b); }
                else       { c1a = fmaf(Aw[k], sa[k], c1a); c2a = fmaf(Bw[k], sb[k], c2a); }
            }
            const float hn = fmaxf((c1a + c1b) + (c2a + c2b), 0.f);

            // at t==0, half1's result is h2[-1] (undefined) -> keep state 0
            vh = (half && t == 0) ? 0.f : hn;
            h2buf[u] = hn;   // half1 lanes: h2[t-1]
        }

        // batched h2 stores — off the serial chain, distinct source regs
        if (st) {
            #pragma unroll
            for (int u = 0; u < 8; ++u) {
                const int t = tb * 8 + u;
                if (u > 0 || tb > 0)
                    h2base[(size_t)(t - 1) * Hn] = h2buf[u];   // h2seq[b, t-1, j]
            }
        }
        xp += 128;   // advance 8 timesteps (16 floats each)
    }

    // Epilogue: h2[T-1] = relu(bias1 + W_ih1*h1[T-1] + W_hh1*h2[T-2])
    {
        float sa[Hn], sb[Hn];
        #pragma unroll
        for (int k = 0; k < Hn; ++k) sa[k] = rdlane(vh, k);        // h1[T-1]
        #pragma unroll
        for (int k = 0; k < Hn; ++k) sb[k] = rdlane(vh, 16 + k);   // h2[T-2]
        float c1a = bias1, c1b = 0.f, c2a = 0.f, c2b = 0.f;
        #pragma unroll
        for (int k = 0; k < Hn; ++k) {
            if (k & 1) { c1b = fmaf(Aw[k], sa[k], c1b); c2b = fmaf(Bw[k], sb[k], c2b); }
            else       { c1a = fmaf(Aw[k], sa[k], c1a); c2a = fmaf(Bw[k], sb[k], c2a); }
        }
        const float hn = fmaxf((c1a + c1b) + (c2a + c2b), 0.f);
        if (st) {
            h2base[(size_t)(Tn - 1) * Hn] = hn;           // h2seq[b, T-1, j]
            hidden[Bn * Hn + b * Hn + (lane - 16)] = hn;  // hidden[1] = h2[T-1]
        }
        if (s1) {
            hidden[b * Hn + lane] = vh;                   // hidden[0] = h1[T-1]
        }
    }
}

// =====================================================================
// K3: logits = h2seq * W_lin^T + b_lin, softmax over 128, f32 out.
// (unchanged — controlled experiment)
// =====================================================================
__global__ __launch_bounds__(256) void k3_outproj(
    const float* __restrict__ h2seq,
    const float* __restrict__ Wlin,
    const float* __restrict__ blin,
    float* __restrict__ out)
{
    const int lane = threadIdx.x & 63;
    const int wid  = blockIdx.x * 4 + (threadIdx.x >> 6);  // grid=1024 -> 4096 waves
    const int g    = lane >> 4;
    const int i    = lane & 15;

    float wl[8][Hn], bl[8];
    #pragma unroll
    for (int s = 0; s < 8; ++s) {
        const int o = i * 8 + s;
        bl[s] = blin[o];
        #pragma unroll
        for (int k = 0; k < Hn; ++k) wl[s][k] = Wlin[o * Hn + k];
    }

    for (int r = wid * 4 + g; r < BTn; r += 4096 * 4) {
        const float hv = (i < Hn) ? h2seq[(size_t)r * Hn + i] : 0.f;
        float acc[8];
        #pragma unroll
        for (int s = 0; s < 8; ++s) acc[s] = bl[s];
        #pragma unroll
        for (int k = 0; k < Hn; ++k) {
            const float hk = __shfl(hv, k, 16);
            #pragma unroll
            for (int s = 0; s < 8; ++s) acc[s] = fmaf(wl[s][k], hk, acc[s]);
        }
        // softmax over this row's 128 logits (16 lanes x 8)
        float m = acc[0];
        #pragma unroll
        for (int s = 1; s < 8; ++s) m = fmaxf(m, acc[s]);
        #pragma unroll
        for (int off = 1; off < 16; off <<= 1) m = fmaxf(m, __shfl_xor(m, off, 16));
        float e[8], ssum = 0.f;
        #pragma unroll
        for (int s = 0; s < 8; ++s) { e[s] = __expf(acc[s] - m); ssum += e[s]; }
        #pragma unroll
        for (int off = 1; off < 16; off <<= 1) ssum += __shfl_xor(ssum, off, 16);
        const float inv = 1.0f / ssum;
        float4* op = reinterpret_cast<float4*>(out + (size_t)r * OUTn + i * 8);
        op[0] = make_float4(e[0] * inv, e[1] * inv, e[2] * inv, e[3] * inv);
        op[1] = make_float4(e[4] * inv, e[5] * inv, e[6] * inv, e[7] * inv);
    }
}

extern "C" void kernel_launch(void* const* d_in, const int* in_sizes, int n_in,
                              void* d_out, int out_size, void* d_ws, size_t ws_size,
                              hipStream_t stream)
{
    const float* x    = (const float*)d_in[0];
    const float* Wih0 = (const float*)d_in[1];
    const float* Whh0 = (const float*)d_in[2];
    const float* bih0 = (const float*)d_in[3];
    const float* bhh0 = (const float*)d_in[4];
    const float* Wih1 = (const float*)d_in[5];
    const float* Whh1 = (const float*)d_in[6];
    const float* bih1 = (const float*)d_in[7];
    const float* bhh1 = (const float*)d_in[8];
    const float* Wlin = (const float*)d_in[9];
    const float* blin = (const float*)d_in[10];

    float* out    = (float*)d_out;
    float* hidden = out + (size_t)BTn * OUTn;    // [2,B,H] tail of d_out

    float* xp0   = (float*)d_ws;                 // BTn*16 f32 = 16.8 MB
    float* h2seq = xp0 + (size_t)BTn * 16;       // BTn*10 f32 = 10.5 MB

    k1_inproj<<<BTn / 256, 256, 0, stream>>>(x, Wih0, bih0, bhh0, xp0);
    k2_recur<<<Bn, 64, 0, stream>>>(xp0, Whh0, Wih1, Whh1, bih1, bhh1, h2seq, hidden);
    k3_outproj<<<1024, 256, 0, stream>>>(h2seq, Wlin, blin, out);
}

// Round 3
// 407.894 us; speedup vs baseline: 1.4006x; 1.3288x over previous
//
#include <hip/hip_runtime.h>

// Problem dims
#define Bn   256
#define Tn   1024
#define INn  128
#define Hn   10
#define OUTn 128
#define BTn  (Bn * Tn)   // 262144 rows

// =====================================================================
// K1: xp0[b,t,j] = sum_i x[b,t,i]*W_ih0[j,i] + b_ih0[j] + b_hh0[j]
// (unchanged — controlled experiment; K2 is the variable)
// =====================================================================
__global__ __launch_bounds__(256) void k1_inproj(
    const float* __restrict__ x,
    const float* __restrict__ Wih0,
    const float* __restrict__ bih0,
    const float* __restrict__ bhh0,
    float* __restrict__ xp0)
{
    __shared__ float Ws[Hn][INn];   // 5 KB
    __shared__ float bs[16];
    const int tid = threadIdx.x;
    for (int idx = tid; idx < Hn * INn; idx += 256)
        Ws[idx / INn][idx % INn] = Wih0[idx];
    if (tid < 16) bs[tid] = (tid < Hn) ? (bih0[tid] + bhh0[tid]) : 0.f;
    __syncthreads();

    const int row = blockIdx.x * 256 + tid;                 // grid = BTn/256
    const float4* xr = reinterpret_cast<const float4*>(x + (size_t)row * INn);

    float acc[Hn];
    #pragma unroll
    for (int j = 0; j < Hn; ++j) acc[j] = bs[j];

    #pragma unroll
    for (int c = 0; c < INn / 4; ++c) {
        float4 v = xr[c];
        #pragma unroll
        for (int j = 0; j < Hn; ++j) {
            acc[j] = fmaf(v.x, Ws[j][c * 4 + 0], acc[j]);
            acc[j] = fmaf(v.y, Ws[j][c * 4 + 1], acc[j]);
            acc[j] = fmaf(v.z, Ws[j][c * 4 + 2], acc[j]);
            acc[j] = fmaf(v.w, Ws[j][c * 4 + 3], acc[j]);
        }
    }
    float4* op = reinterpret_cast<float4*>(xp0 + (size_t)row * 16);
    op[0] = make_float4(acc[0], acc[1], acc[2], acc[3]);
    op[1] = make_float4(acc[4], acc[5], acc[6], acc[7]);
    op[2] = make_float4(acc[8], acc[9], 0.f, 0.f);
    op[3] = make_float4(0.f, 0.f, 0.f, 0.f);
}

// =====================================================================
// K2 v5: fully scalarized recurrence.
//  Evidence trail: v3 (LDS)=296us, v4 (readlane+pin)=260us, both ~600
//  cy/step with VGPR_Count 24/32 — i.e. declared arrays (weights, xbuf,
//  h2buf) never became register-resident; a memory access stayed on the
//  serial chain. v5 removes every array: named scalars only.
//   - weights A0..A9 / B0..B9 / biasv: loaded once, pinned via asm.
//   - x prefetch ring x0..x15 (depth 16: per-step x row is a fresh 64B
//     line, L3-latency ~500cy; at ~100cy/step depth 8 was marginal).
//     Reloads use constant immediate offsets; last block over-reads up
//     to 960B past xp0 into h2seq region (same ws allocation — safe).
//   - h2 stores batched per 8-step block from named y0..y7.
//   - t==0 peeled: no per-step selects/branches in steady state.
//   - lanes 32..63 retired at entry (exec = lower half): no mirror
//     memory traffic; possible 1-pass VALU issue.
// Layout: lanes 0..9 h1 (A=Whh0, B=0), lanes 16..25 h2 one step behind
// (A=Wih1, B=Whh1). State exchange: 20x v_readlane -> SGPR broadcast.
// =====================================================================
static __device__ __forceinline__ float rdlane(float v, int l) {
    return __int_as_float(__builtin_amdgcn_readlane(__float_as_int(v), l));
}
static __device__ __forceinline__ void pinv(float& v) {
    asm volatile("" : "+v"(v));
}

#define RSTEP(XV, YV) do {                                                                  \
    const float sa0=rdlane(vh,0),  sa1=rdlane(vh,1),  sa2=rdlane(vh,2),  sa3=rdlane(vh,3);  \
    const float sa4=rdlane(vh,4),  sa5=rdlane(vh,5),  sa6=rdlane(vh,6),  sa7=rdlane(vh,7);  \
    const float sa8=rdlane(vh,8),  sa9=rdlane(vh,9);                                        \
    const float sb0=rdlane(vh,16), sb1=rdlane(vh,17), sb2=rdlane(vh,18), sb3=rdlane(vh,19); \
    const float sb4=rdlane(vh,20), sb5=rdlane(vh,21), sb6=rdlane(vh,22), sb7=rdlane(vh,23); \
    const float sb8=rdlane(vh,24), sb9=rdlane(vh,25);                                       \
    float c0 = half ? biasv : (XV);                                                         \
    float c1 = 0.f, c2 = 0.f, c3 = 0.f;                                                     \
    c0 = fmaf(A0, sa0, c0); c1 = fmaf(A1, sa1, c1); c2 = fmaf(A2, sa2, c2); c3 = fmaf(A3, sa3, c3); \
    c0 = fmaf(A4, sa4, c0); c1 = fmaf(A5, sa5, c1); c2 = fmaf(A6, sa6, c2); c3 = fmaf(A7, sa7, c3); \
    c0 = fmaf(A8, sa8, c0); c1 = fmaf(A9, sa9, c1); c2 = fmaf(B0, sb0, c2); c3 = fmaf(B1, sb1, c3); \
    c0 = fmaf(B2, sb2, c0); c1 = fmaf(B3, sb3, c1); c2 = fmaf(B4, sb4, c2); c3 = fmaf(B5, sb5, c3); \
    c0 = fmaf(B6, sb6, c0); c1 = fmaf(B7, sb7, c1); c2 = fmaf(B8, sb8, c2); c3 = fmaf(B9, sb9, c3); \
    const float hn_ = fmaxf((c0 + c1) + (c2 + c3), 0.f);                                    \
    vh = hn_; (YV) = hn_;                                                                   \
} while (0)

__global__ __launch_bounds__(64, 1) void k2_recur(
    const float* __restrict__ xp0,
    const float* __restrict__ Whh0,
    const float* __restrict__ Wih1,
    const float* __restrict__ Whh1,
    const float* __restrict__ bih1,
    const float* __restrict__ bhh1,
    float* __restrict__ h2seq,
    float* __restrict__ hidden)   // [2, Bn, Hn] f32 (tail of d_out)
{
    const int lane = threadIdx.x;
    if (lane >= 32) return;                // retire mirror lanes for the whole kernel
    const int half = lane >> 4;            // 0: layer1, 1: layer2 (one step behind)
    const int j    = lane & 15;
    const int jc   = (j < Hn) ? j : (Hn - 1);
    const int b    = blockIdx.x;           // grid = Bn = 256

    const float* Arow = half ? (Wih1 + jc * Hn) : (Whh0 + jc * Hn);
    const float* Brow = half ? (Whh1 + jc * Hn) : (Whh0 + jc * Hn); // half0: dummy, zeroed below
    float A0 = Arow[0], A1 = Arow[1], A2 = Arow[2], A3 = Arow[3], A4 = Arow[4];
    float A5 = Arow[5], A6 = Arow[6], A7 = Arow[7], A8 = Arow[8], A9 = Arow[9];
    float B0 = Brow[0], B1 = Brow[1], B2 = Brow[2], B3 = Brow[3], B4 = Brow[4];
    float B5 = Brow[5], B6 = Brow[6], B7 = Brow[7], B8 = Brow[8], B9 = Brow[9];
    if (!half) { B0=B1=B2=B3=B4=B5=B6=B7=B8=B9=0.f; }
    float biasv = bih1[jc] + bhh1[jc];

    pinv(A0); pinv(A1); pinv(A2); pinv(A3); pinv(A4);
    pinv(A5); pinv(A6); pinv(A7); pinv(A8); pinv(A9);
    pinv(B0); pinv(B1); pinv(B2); pinv(B3); pinv(B4);
    pinv(B5); pinv(B6); pinv(B7); pinv(B8); pinv(B9);
    pinv(biasv);

    const bool st = half && (j < Hn);      // layer-2 output lanes (16..25)
    const bool s1 = !half && (j < Hn);     // layer-1 state lanes (0..9)

    const float* xp = xp0 + (size_t)b * Tn * 16 + j;
    float*       h2w = h2seq + (size_t)b * Tn * Hn + j;

    // prefetch ring, depth 16 (rows t=0..15)
    float x0 = xp[0*16],  x1 = xp[1*16],  x2 = xp[2*16],  x3 = xp[3*16];
    float x4 = xp[4*16],  x5 = xp[5*16],  x6 = xp[6*16],  x7 = xp[7*16];
    float x8 = xp[8*16],  x9 = xp[9*16],  x10 = xp[10*16], x11 = xp[11*16];
    float x12 = xp[12*16], x13 = xp[13*16], x14 = xp[14*16], x15 = xp[15*16];

    // ---- t = 0 (peeled): h1[0] = relu(xp0[b,0,j]); h2 state stays 0 ----
    float vh = half ? 0.f : fmaxf(x0, 0.f);
    x0 = xp[16*16];

    float y0, y1, y2, y3, y4, y5, y6, y7;

    // ---- block 0 remainder: t = 1..7 ----
    RSTEP(x1, y1); x1 = xp[17*16];
    RSTEP(x2, y2); x2 = xp[18*16];
    RSTEP(x3, y3); x3 = xp[19*16];
    RSTEP(x4, y4); x4 = xp[20*16];
    RSTEP(x5, y5); x5 = xp[21*16];
    RSTEP(x6, y6); x6 = xp[22*16];
    RSTEP(x7, y7); x7 = xp[23*16];
    if (st) {
        h2w[0]  = y1; h2w[10] = y2; h2w[20] = y3; h2w[30] = y4;
        h2w[40] = y5; h2w[50] = y6; h2w[60] = y7;      // rows 0..6
    }
    xp += 128; h2w += 70;

    // ---- main: tb = 1..127, alternating LO/HI halves of the ring ----
    #define BLK_LO() do {                                   \
        RSTEP(x0, y0); x0 = xp[16*16];                      \
        RSTEP(x1, y1); x1 = xp[17*16];                      \
        RSTEP(x2, y2); x2 = xp[18*16];                      \
        RSTEP(x3, y3); x3 = xp[19*16];                      \
        RSTEP(x4, y4); x4 = xp[20*16];                      \
        RSTEP(x5, y5); x5 = xp[21*16];                      \
        RSTEP(x6, y6); x6 = xp[22*16];                      \
        RSTEP(x7, y7); x7 = xp[23*16];                      \
        if (st) {                                           \
            h2w[0]  = y0; h2w[10] = y1; h2w[20] = y2; h2w[30] = y3; \
            h2w[40] = y4; h2w[50] = y5; h2w[60] = y6; h2w[70] = y7; \
        }                                                   \
        xp += 128; h2w += 80;                               \
    } while (0)
    #define BLK_HI() do {                                   \
        RSTEP(x8,  y0); x8  = xp[16*16];                    \
        RSTEP(x9,  y1); x9  = xp[17*16];                    \
        RSTEP(x10, y2); x10 = xp[18*16];                    \
        RSTEP(x11, y3); x11 = xp[19*16];                    \
        RSTEP(x12, y4); x12 = xp[20*16];                    \
        RSTEP(x13, y5); x13 = xp[21*16];                    \
        RSTEP(x14, y6); x14 = xp[22*16];                    \
        RSTEP(x15, y7); x15 = xp[23*16];                    \
        if (st) {                                           \
            h2w[0]  = y0; h2w[10] = y1; h2w[20] = y2; h2w[30] = y3; \
            h2w[40] = y4; h2w[50] = y5; h2w[60] = y6; h2w[70] = y7; \
        }                                                   \
        xp += 128; h2w += 80;                               \
    } while (0)

    for (int p = 0; p < 63; ++p) {   // tb = 1,2 .. 125,126
        BLK_HI();                    // odd tb uses ring HI half
        BLK_LO();                    // even tb uses ring LO half
    }
    BLK_HI();                        // tb = 127

    // ---- epilogue: h2[T-1] = relu(biasv + Wih1*h1[T-1] + Whh1*h2[T-2]) ----
    const float h1fin = vh;          // half0 lanes: h1[T-1]
    float yfin;
    RSTEP(0.f, yfin);
    if (st) {
        h2w[0] = yfin;                                 // h2seq[b, T-1, j]
        hidden[Bn * Hn + b * Hn + (lane - 16)] = yfin; // hidden[1]
    }
    if (s1) {
        hidden[b * Hn + lane] = h1fin;                 // hidden[0]
    }
    #undef BLK_LO
    #undef BLK_HI
}

// =====================================================================
// K3: logits = h2seq * W_lin^T + b_lin, softmax over 128, f32 out.
// (unchanged — controlled experiment)
// =====================================================================
__global__ __launch_bounds__(256) void k3_outproj(
    const float* __restrict__ h2seq,
    const float* __restrict__ Wlin,
    const float* __restrict__ blin,
    float* __restrict__ out)
{
    const int lane = threadIdx.x & 63;
    const int wid  = blockIdx.x * 4 + (threadIdx.x >> 6);  // grid=1024 -> 4096 waves
    const int g    = lane >> 4;
    const int i    = lane & 15;

    float wl[8][Hn], bl[8];
    #pragma unroll
    for (int s = 0; s < 8; ++s) {
        const int o = i * 8 + s;
        bl[s] = blin[o];
        #pragma unroll
        for (int k = 0; k < Hn; ++k) wl[s][k] = Wlin[o * Hn + k];
    }

    for (int r = wid * 4 + g; r < BTn; r += 4096 * 4) {
        const float hv = (i < Hn) ? h2seq[(size_t)r * Hn + i] : 0.f;
        float acc[8];
        #pragma unroll
        for (int s = 0; s < 8; ++s) acc[s] = bl[s];
        #pragma unroll
        for (int k = 0; k < Hn; ++k) {
            const float hk = __shfl(hv, k, 16);
            #pragma unroll
            for (int s = 0; s < 8; ++s) acc[s] = fmaf(wl[s][k], hk, acc[s]);
        }
        // softmax over this row's 128 logits (16 lanes x 8)
        float m = acc[0];
        #pragma unroll
        for (int s = 1; s < 8; ++s) m = fmaxf(m, acc[s]);
        #pragma unroll
        for (int off = 1; off < 16; off <<= 1) m = fmaxf(m, __shfl_xor(m, off, 16));
        float e[8], ssum = 0.f;
        #pragma unroll
        for (int s = 0; s < 8; ++s) { e[s] = __expf(acc[s] - m); ssum += e[s]; }
        #pragma unroll
        for (int off = 1; off < 16; off <<= 1) ssum += __shfl_xor(ssum, off, 16);
        const float inv = 1.0f / ssum;
        float4* op = reinterpret_cast<float4*>(out + (size_t)r * OUTn + i * 8);
        op[0] = make_float4(e[0] * inv, e[1] * inv, e[2] * inv, e[3] * inv);
        op[1] = make_float4(e[4] * inv, e[5] * inv, e[6] * inv, e[7] * inv);
    }
}

extern "C" void kernel_launch(void* const* d_in, const int* in_sizes, int n_in,
                              void* d_out, int out_size, void* d_ws, size_t ws_size,
                              hipStream_t stream)
{
    const float* x    = (const float*)d_in[0];
    const float* Wih0 = (const float*)d_in[1];
    const float* Whh0 = (const float*)d_in[2];
    const float* bih0 = (const float*)d_in[3];
    const float* bhh0 = (const float*)d_in[4];
    const float* Wih1 = (const float*)d_in[5];
    const float* Whh1 = (const float*)d_in[6];
    const float* bih1 = (const float*)d_in[7];
    const float* bhh1 = (const float*)d_in[8];
    const float* Wlin = (const float*)d_in[9];
    const float* blin = (const float*)d_in[10];

    float* out    = (float*)d_out;
    float* hidden = out + (size_t)BTn * OUTn;    // [2,B,H] tail of d_out

    float* xp0   = (float*)d_ws;                 // BTn*16 f32 = 16.8 MB
    float* h2seq = xp0 + (size_t)BTn * 16;       // BTn*10 f32 = 10.5 MB

    k1_inproj<<<BTn / 256, 256, 0, stream>>>(x, Wih0, bih0, bhh0, xp0);
    k2_recur<<<Bn, 64, 0, stream>>>(xp0, Whh0, Wih1, Whh1, bih1, bhh1, h2seq, hidden);
    k3_outproj<<<1024, 256, 0, stream>>>(h2seq, Wlin, blin, out);
}